// Round 2
// baseline (678.521 us; speedup 1.0000x reference)
//
#include <hip/hip_runtime.h>

// DynamicGCN: x[100000,384] fp32 -> Linear(384,64) -> GCNConv(64,64) -> ReLU -> GCNConv(64,64)
// All tensors fp32 (reference dtype); edge_index int32. Output fp32.
// Compute: bf16 MFMA with fp32 accumulate (2% rel tolerance allows it).
// Pipeline: deg/dinv -> X1 = x@Wm+bm (MFMA) -> per layer: h=Hin@W fused with
// agg=h*dinv^2+b (self-loop+bias), then per-edge atomic scatter. Last agg/scatter
// target d_out directly.

#define NN 100000
#define NE 800000
#define ROWTILES (NN / 16)   // 6250, exact

typedef unsigned short u16;
typedef __attribute__((ext_vector_type(8))) short short8;   // 8 bf16 = 4 VGPRs (MFMA A/B frag)
typedef __attribute__((ext_vector_type(4))) float f4;       // MFMA C/D frag

__device__ __forceinline__ u16 f2b(float f) {   // RNE fp32 -> bf16
    unsigned int x = __float_as_uint(f);
    x += 0x7fffu + ((x >> 16) & 1u);
    return (u16)(x >> 16);
}

// ---- degree / dinv ---------------------------------------------------------
__global__ __launch_bounds__(256) void deg_init_k(float* __restrict__ deg) {
    int i = blockIdx.x * 256 + threadIdx.x;
    if (i < NN) deg[i] = 1.0f;                  // self-loop weight
}

__global__ __launch_bounds__(256) void deg_edge_k(const int* __restrict__ ei,
                                                  const float* __restrict__ ew,
                                                  float* __restrict__ deg) {
    int e = blockIdx.x * 256 + threadIdx.x;     // grid exact: 3125*256 == NE
    atomicAdd(&deg[ei[NE + e]], ew[e]);         // deg over destinations
}

__global__ __launch_bounds__(256) void rsqrt_k(float* __restrict__ deg) {
    int i = blockIdx.x * 256 + threadIdx.x;
    if (i < NN) deg[i] = rsqrtf(deg[i]);        // deg >= 1 always (self-loop)
}

// ---- MFMA GEMM: out = A[NN,K] @ W[K,64] (+ bias / self-loop epilogue) ------
// mfma_f32_16x16x32_bf16 layouts (m89/m91-verified):
//   A-frag: A[m=lane&15][k=quad*8+j];  B-frag: B[k=quad*8+j][n=lane&15];
//   C/D:    col=lane&15, row=quad*4+reg.
// W (fp32) is converted to bf16 into LDS pre-swizzled so each lane's B-frag is
// one ds_read_b128. A (fp32) converts to bf16 in-register (optional fused relu).
template <int K, bool RELU, bool AGG>
__global__ __launch_bounds__(256) void gcn_gemm(const float* __restrict__ Ain,
                                                const float* __restrict__ Wg,
                                                const float* __restrict__ bias,
                                                const float* __restrict__ dinv,
                                                float* __restrict__ hout,
                                                float* __restrict__ aggout) {
    constexpr int KT = K / 32;
    __shared__ u16 Blds[KT * 256 * 8];
    int tid = threadIdx.x;
    for (int idx = tid; idx < KT * 256; idx += 256) {
        int kt = idx >> 8;
        int rem = idx & 255;
        int ct = rem >> 6;
        int ln = rem & 63;
        int kb = kt * 32 + (ln >> 4) * 8;
        int col = ct * 16 + (ln & 15);
#pragma unroll
        for (int j = 0; j < 8; j++)
            Blds[idx * 8 + j] = f2b(Wg[(kb + j) * 64 + col]);
    }
    __syncthreads();

    int wave = tid >> 6, lane = tid & 63;
    int rowtile = blockIdx.x * 4 + wave;
    if (rowtile >= ROWTILES) return;
    int rowbase = rowtile * 16;
    int m = lane & 15, quad = lane >> 4;

    f4 acc[4];
#pragma unroll
    for (int ct = 0; ct < 4; ct++) acc[ct] = 0.0f;

    const short8* Bfrag = (const short8*)Blds;
#pragma unroll
    for (int kt = 0; kt < KT; kt++) {
        const f4* p = (const f4*)&Ain[(rowbase + m) * K + kt * 32 + quad * 8];
        f4 v0 = p[0], v1 = p[1];
        short8 af;
#pragma unroll
        for (int j = 0; j < 4; j++) {
            float a0 = v0[j], a1 = v1[j];
            if (RELU) { a0 = fmaxf(a0, 0.0f); a1 = fmaxf(a1, 0.0f); }
            af[j]     = (short)f2b(a0);
            af[4 + j] = (short)f2b(a1);
        }
#pragma unroll
        for (int ct = 0; ct < 4; ct++) {
            short8 bf = Bfrag[(kt * 4 + ct) * 64 + lane];
            acc[ct] = __builtin_amdgcn_mfma_f32_16x16x32_bf16(af, bf, acc[ct], 0, 0, 0);
        }
    }

    if (!AGG) {
        // hout = A@W + bias   (input projection)
#pragma unroll
        for (int ct = 0; ct < 4; ct++) {
            int col = ct * 16 + m;
            float bc = bias[col];
#pragma unroll
            for (int r = 0; r < 4; r++) {
                int row = rowbase + quad * 4 + r;
                hout[row * 64 + col] = acc[ct][r] + bc;
            }
        }
    } else {
        // hout = A@W ;  aggout = hout*dinv^2 + bias  (self-loop + bias init)
        float d2[4];
#pragma unroll
        for (int r = 0; r < 4; r++) {
            float d = dinv[rowbase + quad * 4 + r];
            d2[r] = d * d;
        }
#pragma unroll
        for (int ct = 0; ct < 4; ct++) {
            int col = ct * 16 + m;
            float bc = bias[col];
#pragma unroll
            for (int r = 0; r < 4; r++) {
                int row = rowbase + quad * 4 + r;
                float v = acc[ct][r];
                hout[row * 64 + col] = v;
                aggout[row * 64 + col] = fmaf(v, d2[r], bc);
            }
        }
    }
}

// ---- edge scatter: one wave per edge, lane = feature ----------------------
__global__ __launch_bounds__(256) void scatter_k(const int* __restrict__ ei,
                                                 const float* __restrict__ ew,
                                                 const float* __restrict__ dinv,
                                                 const float* __restrict__ h,
                                                 float* __restrict__ out) {
    int e = blockIdx.x * 4 + (threadIdx.x >> 6);   // grid exact: 200000*4 == NE
    int lane = threadIdx.x & 63;
    int src = ei[e];
    int dst = ei[NE + e];
    float coef = dinv[src] * ew[e] * dinv[dst];
    float v = h[src * 64 + lane] * coef;
    atomicAdd(&out[dst * 64 + lane], v);
}

extern "C" void kernel_launch(void* const* d_in, const int* in_sizes, int n_in,
                              void* d_out, int out_size, void* d_ws, size_t ws_size,
                              hipStream_t stream) {
    const float* x  = (const float*)d_in[0];
    const int*   ei = (const int*)d_in[1];
    const float* ew = (const float*)d_in[2];
    const float* Wm = (const float*)d_in[3];
    const float* bm = (const float*)d_in[4];
    const float* W1 = (const float*)d_in[5];
    const float* b1 = (const float*)d_in[6];
    const float* W2 = (const float*)d_in[7];
    const float* b2 = (const float*)d_in[8];
    float* out = (float*)d_out;

    // workspace: dinv (0.4 MB, 1 MB slot) + 3 x [NN,64] fp32 (25.6 MB each)
    float* dinv = (float*)d_ws;
    float* buf0 = (float*)((char*)d_ws + (1 << 20));
    float* buf1 = buf0 + (size_t)NN * 64;
    float* buf2 = buf1 + (size_t)NN * 64;

    deg_init_k<<<391, 256, 0, stream>>>(dinv);
    deg_edge_k<<<3125, 256, 0, stream>>>(ei, ew, dinv);
    rsqrt_k<<<391, 256, 0, stream>>>(dinv);

    // X1 = x @ Wm + bm                        -> buf0
    gcn_gemm<384, false, false><<<1563, 256, 0, stream>>>(x, Wm, bm, nullptr, buf0, nullptr);
    // layer 1: h1 = X1@W1 -> buf1 ; agg1 = h1*dinv^2 + b1 -> buf2
    gcn_gemm<64, false, true><<<1563, 256, 0, stream>>>(buf0, W1, b1, dinv, buf1, buf2);
    scatter_k<<<200000, 256, 0, stream>>>(ei, ew, dinv, buf1, buf2);
    // layer 2: h2 = relu(agg1)@W2 -> buf0 ; agg2 = h2*dinv^2 + b2 -> d_out
    gcn_gemm<64, true, true><<<1563, 256, 0, stream>>>(buf2, W2, b2, dinv, buf0, out);
    scatter_k<<<200000, 256, 0, stream>>>(ei, ew, dinv, buf0, out);
}

// Round 3
// 459.663 us; speedup vs baseline: 1.4761x; 1.4761x over previous
//
#include <hip/hip_runtime.h>

// DynamicGCN: x[100000,384] fp32 -> Linear(384,64) -> GCNConv(64,64) -> ReLU -> GCNConv(64,64)
// Round 3: atomic scatter replaced by device-built CSR + register gather.
// Intermediates (X1, h, agg) stored bf16; fp32 accumulation everywhere.
// Pipeline: init -> deg/count -> rsqrt -> scan(block,sums,fixup) -> fill(CSR)
//   -> gemm_proj(x->X1b) -> gemm1(X1b->hb) -> gather1(hb->aggb, +b1, relu)
//   -> gemm2(aggb->hb) -> gather2(hb->d_out fp32, +b2)

#define NN 100000
#define NE 800000
#define ROWTILES (NN / 16)   // 6250, exact

typedef unsigned short u16;
typedef __attribute__((ext_vector_type(8))) short short8;   // 8 bf16 (MFMA A/B frag)
typedef __attribute__((ext_vector_type(4))) float f4;       // MFMA C/D frag
typedef __attribute__((ext_vector_type(4))) unsigned short u16x4;

__device__ __forceinline__ u16 f2b(float f) {   // RNE fp32 -> bf16
    unsigned int x = __float_as_uint(f);
    x += 0x7fffu + ((x >> 16) & 1u);
    return (u16)(x >> 16);
}
__device__ __forceinline__ float b2f(u16 u) {
    return __uint_as_float(((unsigned int)u) << 16);
}

// ---- init: deg=1 (self-loop), count=0 -------------------------------------
__global__ __launch_bounds__(256) void init_k(float* __restrict__ deg,
                                              int* __restrict__ count) {
    int i = blockIdx.x * 256 + threadIdx.x;
    if (i < NN) { deg[i] = 1.0f; count[i] = 0; }
}

__global__ __launch_bounds__(256) void deg_count_k(const int* __restrict__ ei,
                                                   const float* __restrict__ ew,
                                                   float* __restrict__ deg,
                                                   int* __restrict__ count) {
    int e = blockIdx.x * 256 + threadIdx.x;     // grid exact: 3125*256 == NE
    int dst = ei[NE + e];
    atomicAdd(&deg[dst], ew[e]);
    atomicAdd(&count[dst], 1);
}

__global__ __launch_bounds__(256) void rsqrt_k(float* __restrict__ deg) {
    int i = blockIdx.x * 256 + threadIdx.x;
    if (i < NN) deg[i] = rsqrtf(deg[i]);        // deg >= 1 (self-loop)
}

// ---- exclusive scan of count -> base (3 kernels) --------------------------
__global__ __launch_bounds__(1024) void scan_block_k(const int* __restrict__ count,
                                                     int* __restrict__ base,
                                                     int* __restrict__ bsum) {
    __shared__ int s[1024];
    int t = threadIdx.x;
    int i = blockIdx.x * 1024 + t;
    int v = (i < NN) ? count[i] : 0;
    s[t] = v;
    __syncthreads();
#pragma unroll
    for (int off = 1; off < 1024; off <<= 1) {
        int u = (t >= off) ? s[t - off] : 0;
        __syncthreads();
        s[t] += u;
        __syncthreads();
    }
    if (i < NN) base[i] = s[t] - v;             // exclusive
    if (t == 1023) bsum[blockIdx.x] = s[1023];
}

__global__ __launch_bounds__(128) void scan_sums_k(const int* __restrict__ bsum,
                                                   int* __restrict__ boff) {
    __shared__ int s[128];
    int t = threadIdx.x;
    int v = (t < 98) ? bsum[t] : 0;
    s[t] = v;
    __syncthreads();
#pragma unroll
    for (int off = 1; off < 128; off <<= 1) {
        int u = (t >= off) ? s[t - off] : 0;
        __syncthreads();
        s[t] += u;
        __syncthreads();
    }
    if (t < 98) boff[t] = s[t] - v;             // exclusive
}

__global__ __launch_bounds__(256) void fixup_k(int* __restrict__ base,
                                               int* __restrict__ cursor,
                                               const int* __restrict__ boff) {
    int i = blockIdx.x * 256 + threadIdx.x;
    if (i < NN) {
        int b = base[i] + boff[i >> 10];
        base[i] = b;
        cursor[i] = b;
    }
}

// ---- fill CSR: e2[pos] = {src, coef} --------------------------------------
__global__ __launch_bounds__(256) void fill_k(const int* __restrict__ ei,
                                              const float* __restrict__ ew,
                                              const float* __restrict__ dinv,
                                              int* __restrict__ cursor,
                                              int2* __restrict__ e2) {
    int e = blockIdx.x * 256 + threadIdx.x;     // grid exact
    int src = ei[e];
    int dst = ei[NE + e];
    float coef = dinv[src] * ew[e] * dinv[dst];
    int pos = atomicAdd(&cursor[dst], 1);
    e2[pos] = make_int2(src, __float_as_int(coef));
}

// ---- MFMA GEMM: hout_b16 = A[NN,K] @ W[K,64] (+ bias) ---------------------
// mfma_f32_16x16x32_bf16: A[m=lane&15][k=quad*8+j]; B[k=quad*8+j][n=lane&15];
// C/D: col=lane&15, row=quad*4+reg. W fp32 -> bf16 LDS pre-swizzled (ds_read_b128).
template <int K, bool A_FP32, bool BIAS>
__global__ __launch_bounds__(256) void gcn_gemm(const void* __restrict__ Ain,
                                                const float* __restrict__ Wg,
                                                const float* __restrict__ bias,
                                                u16* __restrict__ hout) {
    constexpr int KT = K / 32;
    __shared__ u16 Blds[KT * 256 * 8];
    int tid = threadIdx.x;
    for (int idx = tid; idx < KT * 256; idx += 256) {
        int kt = idx >> 8;
        int rem = idx & 255;
        int ct = rem >> 6;
        int ln = rem & 63;
        int kb = kt * 32 + (ln >> 4) * 8;
        int col = ct * 16 + (ln & 15);
#pragma unroll
        for (int j = 0; j < 8; j++)
            Blds[idx * 8 + j] = f2b(Wg[(kb + j) * 64 + col]);
    }
    __syncthreads();

    int wave = tid >> 6, lane = tid & 63;
    int rowtile = blockIdx.x * 4 + wave;
    if (rowtile >= ROWTILES) return;
    int rowbase = rowtile * 16;
    int m = lane & 15, quad = lane >> 4;

    f4 acc[4];
#pragma unroll
    for (int ct = 0; ct < 4; ct++) acc[ct] = 0.0f;

    const short8* Bfrag = (const short8*)Blds;
#pragma unroll
    for (int kt = 0; kt < KT; kt++) {
        short8 af;
        if (A_FP32) {
            const float* A = (const float*)Ain;
            const f4* p = (const f4*)&A[(rowbase + m) * K + kt * 32 + quad * 8];
            f4 v0 = p[0], v1 = p[1];
#pragma unroll
            for (int j = 0; j < 4; j++) {
                af[j]     = (short)f2b(v0[j]);
                af[4 + j] = (short)f2b(v1[j]);
            }
        } else {
            const u16* A = (const u16*)Ain;
            af = *(const short8*)&A[(rowbase + m) * K + kt * 32 + quad * 8];
        }
#pragma unroll
        for (int ct = 0; ct < 4; ct++) {
            short8 bf = Bfrag[(kt * 4 + ct) * 64 + lane];
            acc[ct] = __builtin_amdgcn_mfma_f32_16x16x32_bf16(af, bf, acc[ct], 0, 0, 0);
        }
    }

#pragma unroll
    for (int ct = 0; ct < 4; ct++) {
        int col = ct * 16 + m;
        float bc = BIAS ? bias[col] : 0.0f;
#pragma unroll
        for (int r = 0; r < 4; r++) {
            int row = rowbase + quad * 4 + r;
            hout[row * 64 + col] = f2b(acc[ct][r] + bc);
        }
    }
}

// ---- gather: out[dst] = bias + dinv^2*h[dst] + sum coef*h[src] ------------
// 16 threads per dst row; thread ch handles features [ch*4, ch*4+4) (bf16x4).
template <bool OUT_FP32, bool RELU>
__global__ __launch_bounds__(256) void gather_k(const int2* __restrict__ e2,
                                                const int* __restrict__ base,
                                                const int* __restrict__ count,
                                                const float* __restrict__ dinv,
                                                const u16* __restrict__ hb,
                                                const float* __restrict__ bias,
                                                void* __restrict__ outp) {
    int tid = threadIdx.x;
    int dst = blockIdx.x * 16 + (tid >> 4);    // grid exact: 6250*16 == NN
    int ch = tid & 15;
    int b0 = base[dst];
    int cnt = count[dst];
    float d = dinv[dst];
    float d2 = d * d;

    u16x4 hs = *(const u16x4*)&hb[dst * 64 + ch * 4];
    f4 acc;
#pragma unroll
    for (int j = 0; j < 4; j++)
        acc[j] = fmaf(d2, b2f(hs[j]), bias[ch * 4 + j]);

    int end = b0 + cnt;
    int2 sc = (cnt > 0) ? e2[b0] : make_int2(0, 0);
    for (int i = b0; i < end; i++) {
        int2 cur = sc;
        if (i + 1 < end) sc = e2[i + 1];       // prefetch next edge record
        int src = cur.x;
        float c = __int_as_float(cur.y);
        u16x4 hv = *(const u16x4*)&hb[src * 64 + ch * 4];
#pragma unroll
        for (int j = 0; j < 4; j++)
            acc[j] = fmaf(c, b2f(hv[j]), acc[j]);
    }

    if (OUT_FP32) {
        ((f4*)outp)[dst * 16 + ch] = acc;
    } else {
        u16x4 o;
#pragma unroll
        for (int j = 0; j < 4; j++) {
            float v = acc[j];
            if (RELU) v = fmaxf(v, 0.0f);
            o[j] = f2b(v);
        }
        ((u16x4*)outp)[dst * 16 + ch] = o;
    }
}

extern "C" void kernel_launch(void* const* d_in, const int* in_sizes, int n_in,
                              void* d_out, int out_size, void* d_ws, size_t ws_size,
                              hipStream_t stream) {
    const float* x  = (const float*)d_in[0];
    const int*   ei = (const int*)d_in[1];
    const float* ew = (const float*)d_in[2];
    const float* Wm = (const float*)d_in[3];
    const float* bm = (const float*)d_in[4];
    const float* W1 = (const float*)d_in[5];
    const float* b1 = (const float*)d_in[6];
    const float* W2 = (const float*)d_in[7];
    const float* b2 = (const float*)d_in[8];
    float* out = (float*)d_out;

    // ws layout (offsets in bytes)
    char* w = (char*)d_ws;
    float* dinv   = (float*)(w);                    // NN f32
    int*   count  = (int*)(w + (512 << 10));        // NN i32
    int*   base   = (int*)(w + (1 << 20));          // NN i32
    int*   cursor = (int*)(w + (1536 << 10));       // NN i32
    int*   bsum   = (int*)(w + (2 << 20));          // 98 i32
    int*   boff   = (int*)(w + (2 << 20) + 4096);   // 98 i32
    int2*  e2     = (int2*)(w + (4 << 20));         // NE int2 (6.4 MB)
    u16*   X1b    = (u16*)(w + (16u << 20));        // NN*64 bf16 (12.8 MB)
    u16*   hb     = (u16*)(w + (32u << 20));        // NN*64 bf16
    u16*   aggb   = (u16*)(w + (48u << 20));        // NN*64 bf16

    init_k<<<391, 256, 0, stream>>>(dinv, count);
    deg_count_k<<<3125, 256, 0, stream>>>(ei, ew, dinv, count);
    rsqrt_k<<<391, 256, 0, stream>>>(dinv);
    scan_block_k<<<98, 1024, 0, stream>>>(count, base, bsum);
    scan_sums_k<<<1, 128, 0, stream>>>(bsum, boff);
    fixup_k<<<391, 256, 0, stream>>>(base, cursor, boff);
    fill_k<<<3125, 256, 0, stream>>>(ei, ew, dinv, cursor, e2);

    // X1 = x @ Wm + bm (bf16)
    gcn_gemm<384, true, true><<<1563, 256, 0, stream>>>(x, Wm, bm, X1b);
    // layer 1: h1 = X1@W1 ; agg1 = relu(gather(h1) + b1)
    gcn_gemm<64, false, false><<<1563, 256, 0, stream>>>(X1b, W1, nullptr, hb);
    gather_k<false, true><<<6250, 256, 0, stream>>>(e2, base, count, dinv, hb, b1, aggb);
    // layer 2: h2 = agg1@W2 ; out = gather(h2) + b2 (fp32)
    gcn_gemm<64, false, false><<<1563, 256, 0, stream>>>(aggb, W2, nullptr, hb);
    gather_k<true, false><<<6250, 256, 0, stream>>>(e2, base, count, dinv, hb, b2, out);
}

// Round 4
// 449.560 us; speedup vs baseline: 1.5093x; 1.0225x over previous
//
#include <hip/hip_runtime.h>

// DynamicGCN: x[100000,384] fp32 -> Linear(384,64) -> GCNConv(64,64) -> ReLU -> GCNConv(64,64)
// Round 4: algebraic fusion.
//   Layer1: A*( (x Wm + bm) W1 ) + b1 = A*(x (Wm W1)) + rowsum(A)*(bm W1) + b1
//     -> precompute Wf = Wm@W1, bmW1 = bm@W1; ONE K=384 GEMM (x@Wf); gather adds
//        rowsum term (rowsum accumulated for free in the gather loop) + bias + relu.
//   Layer2: A*(relu1 W2) + b2 = (A*relu1) W2 + b2 -> gather first, final MFMA GEMM
//        writes d_out fp32 with bias.
// CSR built on device (count/scan/fill), coef = dinv[src]*w*dinv[dst] precomputed.
// Intermediates bf16, accumulation fp32. Gather: 16 thr/row, edge-unroll x2 ILP.

#define NN 100000
#define NE 800000

typedef unsigned short u16;
typedef __attribute__((ext_vector_type(8))) short short8;   // 8 bf16 (MFMA A/B frag)
typedef __attribute__((ext_vector_type(4))) float f4;       // MFMA C/D frag
typedef __attribute__((ext_vector_type(4))) unsigned short u16x4;

__device__ __forceinline__ u16 f2b(float f) {   // RNE fp32 -> bf16
    unsigned int x = __float_as_uint(f);
    x += 0x7fffu + ((x >> 16) & 1u);
    return (u16)(x >> 16);
}
__device__ __forceinline__ float b2f(u16 u) {
    return __uint_as_float(((unsigned int)u) << 16);
}

// ---- init: deg=1 (self-loop), count=0 -------------------------------------
__global__ __launch_bounds__(256) void init_k(float* __restrict__ deg,
                                              int* __restrict__ count) {
    int i = blockIdx.x * 256 + threadIdx.x;
    if (i < NN) { deg[i] = 1.0f; count[i] = 0; }
}

__global__ __launch_bounds__(256) void deg_count_k(const int* __restrict__ ei,
                                                   const float* __restrict__ ew,
                                                   float* __restrict__ deg,
                                                   int* __restrict__ count) {
    int e = blockIdx.x * 256 + threadIdx.x;     // grid exact: 3125*256 == NE
    int dst = ei[NE + e];
    atomicAdd(&deg[dst], ew[e]);
    atomicAdd(&count[dst], 1);
}

__global__ __launch_bounds__(256) void rsqrt_k(float* __restrict__ deg) {
    int i = blockIdx.x * 256 + threadIdx.x;
    if (i < NN) deg[i] = rsqrtf(deg[i]);        // deg >= 1 (self-loop)
}

// ---- exclusive scan of count -> base --------------------------------------
__global__ __launch_bounds__(1024) void scan_block_k(const int* __restrict__ count,
                                                     int* __restrict__ base,
                                                     int* __restrict__ bsum) {
    __shared__ int s[1024];
    int t = threadIdx.x;
    int i = blockIdx.x * 1024 + t;
    int v = (i < NN) ? count[i] : 0;
    s[t] = v;
    __syncthreads();
#pragma unroll
    for (int off = 1; off < 1024; off <<= 1) {
        int u = (t >= off) ? s[t - off] : 0;
        __syncthreads();
        s[t] += u;
        __syncthreads();
    }
    if (i < NN) base[i] = s[t] - v;             // exclusive
    if (t == 1023) bsum[blockIdx.x] = s[1023];
}

__global__ __launch_bounds__(128) void scan_sums_k(const int* __restrict__ bsum,
                                                   int* __restrict__ boff) {
    __shared__ int s[128];
    int t = threadIdx.x;
    int v = (t < 98) ? bsum[t] : 0;
    s[t] = v;
    __syncthreads();
#pragma unroll
    for (int off = 1; off < 128; off <<= 1) {
        int u = (t >= off) ? s[t - off] : 0;
        __syncthreads();
        s[t] += u;
        __syncthreads();
    }
    if (t < 98) boff[t] = s[t] - v;             // exclusive
}

__global__ __launch_bounds__(256) void fixup_k(int* __restrict__ base,
                                               int* __restrict__ cursor,
                                               const int* __restrict__ boff) {
    int i = blockIdx.x * 256 + threadIdx.x;
    if (i < NN) {
        int b = base[i] + boff[i >> 10];
        base[i] = b;
        cursor[i] = b;
    }
}

// ---- fill CSR: e2[pos] = {src, coef} --------------------------------------
__global__ __launch_bounds__(256) void fill_k(const int* __restrict__ ei,
                                              const float* __restrict__ ew,
                                              const float* __restrict__ dinv,
                                              int* __restrict__ cursor,
                                              int2* __restrict__ e2) {
    int e = blockIdx.x * 256 + threadIdx.x;     // grid exact
    int src = ei[e];
    int dst = ei[NE + e];
    float coef = dinv[src] * ew[e] * dinv[dst];
    int pos = atomicAdd(&cursor[dst], 1);
    e2[pos] = make_int2(src, __float_as_int(coef));
}

// ---- bmW1[c] = sum_k bm[k] * W1[k][c] -------------------------------------
__global__ __launch_bounds__(64) void bvec_k(const float* __restrict__ bm,
                                             const float* __restrict__ W1,
                                             float* __restrict__ bmw1) {
    int c = threadIdx.x;
    float a = 0.0f;
    for (int k = 0; k < 64; k++) a = fmaf(bm[k], W1[k * 64 + c], a);
    bmw1[c] = a;
}

// ---- MFMA GEMM: out = A[rows,K] @ W[K,64] (+ bias) ------------------------
// mfma_f32_16x16x32_bf16: A[m=lane&15][k=quad*8+j]; B[k=quad*8+j][n=lane&15];
// C/D: col=lane&15, row=quad*4+reg. W fp32 -> bf16 LDS pre-swizzled (ds_read_b128).
template <int K, bool A_FP32, bool BIAS, bool OUT_F32>
__global__ __launch_bounds__(256) void gcn_gemm(const void* __restrict__ Ain,
                                                const float* __restrict__ Wg,
                                                const float* __restrict__ bias,
                                                void* __restrict__ outp,
                                                int rowtiles) {
    constexpr int KT = K / 32;
    __shared__ u16 Blds[KT * 256 * 8];
    int tid = threadIdx.x;
    for (int idx = tid; idx < KT * 256; idx += 256) {
        int kt = idx >> 8;
        int rem = idx & 255;
        int ct = rem >> 6;
        int ln = rem & 63;
        int kb = kt * 32 + (ln >> 4) * 8;
        int col = ct * 16 + (ln & 15);
#pragma unroll
        for (int j = 0; j < 8; j++)
            Blds[idx * 8 + j] = f2b(Wg[(kb + j) * 64 + col]);
    }
    __syncthreads();

    int wave = tid >> 6, lane = tid & 63;
    int rowtile = blockIdx.x * 4 + wave;
    if (rowtile >= rowtiles) return;
    int rowbase = rowtile * 16;
    int m = lane & 15, quad = lane >> 4;

    f4 acc[4];
#pragma unroll
    for (int ct = 0; ct < 4; ct++) acc[ct] = 0.0f;

    const short8* Bfrag = (const short8*)Blds;
#pragma unroll
    for (int kt = 0; kt < KT; kt++) {
        short8 af;
        if (A_FP32) {
            const float* A = (const float*)Ain;
            const f4* p = (const f4*)&A[(size_t)(rowbase + m) * K + kt * 32 + quad * 8];
            f4 v0 = p[0], v1 = p[1];
#pragma unroll
            for (int j = 0; j < 4; j++) {
                af[j]     = (short)f2b(v0[j]);
                af[4 + j] = (short)f2b(v1[j]);
            }
        } else {
            const u16* A = (const u16*)Ain;
            af = *(const short8*)&A[(size_t)(rowbase + m) * K + kt * 32 + quad * 8];
        }
#pragma unroll
        for (int ct = 0; ct < 4; ct++) {
            short8 bf = Bfrag[(kt * 4 + ct) * 64 + lane];
            acc[ct] = __builtin_amdgcn_mfma_f32_16x16x32_bf16(af, bf, acc[ct], 0, 0, 0);
        }
    }

#pragma unroll
    for (int ct = 0; ct < 4; ct++) {
        int col = ct * 16 + m;
        float bc = BIAS ? bias[col] : 0.0f;
#pragma unroll
        for (int r = 0; r < 4; r++) {
            int row = rowbase + quad * 4 + r;
            float v = acc[ct][r] + bc;
            if (OUT_F32) ((float*)outp)[(size_t)row * 64 + col] = v;
            else         ((u16*)outp)[(size_t)row * 64 + col] = f2b(v);
        }
    }
}

// ---- gather: out[dst] = [relu](d^2*h[dst] + sum coef*h[src] [+ s*bmw1 + b1])
// 16 threads per dst row; thread ch handles features [ch*4, ch*4+4) (bf16x4).
// Edge loop unrolled x2: two independent gathers in flight per iteration.
template <bool L1>
__global__ __launch_bounds__(256) void gather_k(const int2* __restrict__ e2,
                                                const int* __restrict__ base,
                                                const int* __restrict__ count,
                                                const float* __restrict__ dinv,
                                                const u16* __restrict__ hb,
                                                const float* __restrict__ bmw1,
                                                const float* __restrict__ b1,
                                                u16* __restrict__ outb) {
    int tid = threadIdx.x;
    int dst = blockIdx.x * 16 + (tid >> 4);    // grid exact: 6250*16 == NN
    int ch = tid & 15;
    int b0 = base[dst];
    int cnt = count[dst];
    float d = dinv[dst];
    float d2 = d * d;

    f4 acc = 0.0f;
    float cs = 0.0f;                           // running sum of coefs (rowsum)
    int i = b0, end = b0 + cnt;
    for (; i + 1 < end; i += 2) {
        int2 ea = e2[i];
        int2 eb = e2[i + 1];
        float ca = __int_as_float(ea.y);
        float cb = __int_as_float(eb.y);
        u16x4 ha = *(const u16x4*)&hb[(size_t)ea.x * 64 + ch * 4];
        u16x4 hv = *(const u16x4*)&hb[(size_t)eb.x * 64 + ch * 4];
#pragma unroll
        for (int j = 0; j < 4; j++) acc[j] = fmaf(ca, b2f(ha[j]), acc[j]);
#pragma unroll
        for (int j = 0; j < 4; j++) acc[j] = fmaf(cb, b2f(hv[j]), acc[j]);
        if (L1) cs += ca + cb;
    }
    if (i < end) {
        int2 ea = e2[i];
        float ca = __int_as_float(ea.y);
        u16x4 ha = *(const u16x4*)&hb[(size_t)ea.x * 64 + ch * 4];
#pragma unroll
        for (int j = 0; j < 4; j++) acc[j] = fmaf(ca, b2f(ha[j]), acc[j]);
        if (L1) cs += ca;
    }

    u16x4 hs = *(const u16x4*)&hb[(size_t)dst * 64 + ch * 4];
#pragma unroll
    for (int j = 0; j < 4; j++) acc[j] = fmaf(d2, b2f(hs[j]), acc[j]);

    u16x4 o;
    if (L1) {
        float s = d2 + cs;                     // rowsum of normalized adjacency
#pragma unroll
        for (int j = 0; j < 4; j++) {
            float v = fmaf(s, bmw1[ch * 4 + j], acc[j]) + b1[ch * 4 + j];
            o[j] = f2b(fmaxf(v, 0.0f));        // fused relu
        }
    } else {
#pragma unroll
        for (int j = 0; j < 4; j++) o[j] = f2b(acc[j]);
    }
    ((u16x4*)outb)[(size_t)dst * 16 + ch] = o;
}

extern "C" void kernel_launch(void* const* d_in, const int* in_sizes, int n_in,
                              void* d_out, int out_size, void* d_ws, size_t ws_size,
                              hipStream_t stream) {
    const float* x  = (const float*)d_in[0];
    const int*   ei = (const int*)d_in[1];
    const float* ew = (const float*)d_in[2];
    const float* Wm = (const float*)d_in[3];
    const float* bm = (const float*)d_in[4];
    const float* W1 = (const float*)d_in[5];
    const float* b1 = (const float*)d_in[6];
    const float* W2 = (const float*)d_in[7];
    const float* b2 = (const float*)d_in[8];
    float* out = (float*)d_out;

    // ws layout (offsets in bytes)
    char* w = (char*)d_ws;
    float* dinv   = (float*)(w);                    // NN f32
    int*   count  = (int*)(w + (512 << 10));        // NN i32
    int*   base   = (int*)(w + (1 << 20));          // NN i32
    int*   cursor = (int*)(w + (1536 << 10));       // NN i32
    int*   bsum   = (int*)(w + (2 << 20));          // 98 i32
    int*   boff   = (int*)(w + (2 << 20) + 4096);   // 98 i32
    float* bmw1   = (float*)(w + (2 << 20) + 8192); // 64 f32
    float* Wf     = (float*)(w + (3 << 20));        // 384*64 f32 (98 KB)
    int2*  e2     = (int2*)(w + (4 << 20));         // NE int2 (6.4 MB)
    u16*   hb     = (u16*)(w + (16u << 20));        // NN*64 bf16 (12.8 MB)
    u16*   aggb   = (u16*)(w + (32u << 20));        // NN*64 bf16
    u16*   aggx2  = (u16*)(w + (48u << 20));        // NN*64 bf16

    // CSR build + norm
    init_k<<<391, 256, 0, stream>>>(dinv, count);
    deg_count_k<<<3125, 256, 0, stream>>>(ei, ew, dinv, count);
    rsqrt_k<<<391, 256, 0, stream>>>(dinv);
    scan_block_k<<<98, 1024, 0, stream>>>(count, base, bsum);
    scan_sums_k<<<1, 128, 0, stream>>>(bsum, boff);
    fixup_k<<<391, 256, 0, stream>>>(base, cursor, boff);
    fill_k<<<3125, 256, 0, stream>>>(ei, ew, dinv, cursor, e2);

    // fused weights: Wf = Wm @ W1 (384x64, fp32), bmw1 = bm @ W1
    bvec_k<<<1, 64, 0, stream>>>(bm, W1, bmw1);
    gcn_gemm<64, true, false, true><<<6, 256, 0, stream>>>(Wm, W1, nullptr, Wf, 24);

    // h1' = x @ Wf  (bf16)
    gcn_gemm<384, true, false, false><<<1563, 256, 0, stream>>>(x, Wf, nullptr, hb, 6250);
    // agg1 = relu(gather(h1') + s*bmw1 + b1)  (bf16)
    gather_k<true><<<6250, 256, 0, stream>>>(e2, base, count, dinv, hb, bmw1, b1, aggb);
    // aggx2 = gather(agg1)  (bf16)
    gather_k<false><<<6250, 256, 0, stream>>>(e2, base, count, dinv, aggb, nullptr, nullptr, aggx2);
    // out = aggx2 @ W2 + b2  (fp32)
    gcn_gemm<64, false, true, true><<<1563, 256, 0, stream>>>(aggx2, W2, b2, out, 6250);
}

// Round 5
// 425.342 us; speedup vs baseline: 1.5952x; 1.0569x over previous
//
#include <hip/hip_runtime.h>

// DynamicGCN: x[100000,384] fp32 -> Linear(384,64) -> GCNConv(64,64) -> ReLU -> GCNConv(64,64)
// Round 5: 7 dispatches total.
//   - Bucketed CSR (64 slots/dst, atomic fill, no scan; P(overflow) ~ 1e-33, guarded)
//   - fill computes coef = rsqrt(deg_s)*w*rsqrt(deg_d) on the fly (no rsqrt pass)
//   - Layer1 fused: Wf = Wm@W1 precomputed; ONE K=384 GEMM; gather1 adds
//     rowsum(A)*(bm@W1) (bm@W1 computed per-block in LDS) + b1 + relu
//   - Layer2 commuted: gather2 fused with final MFMA GEMM (A-tile in LDS) -> d_out
// Intermediates bf16, accumulation fp32 throughout.

#define NN 100000
#define NE 800000
#define BC 64          // bucket capacity per dst row

typedef unsigned short u16;
typedef __attribute__((ext_vector_type(8))) short short8;   // 8 bf16 (MFMA A/B frag)
typedef __attribute__((ext_vector_type(4))) float f4;       // MFMA C/D frag
typedef __attribute__((ext_vector_type(4))) unsigned short u16x4;

__device__ __forceinline__ u16 f2b(float f) {   // RNE fp32 -> bf16
    unsigned int x = __float_as_uint(f);
    x += 0x7fffu + ((x >> 16) & 1u);
    return (u16)(x >> 16);
}
__device__ __forceinline__ float b2f(u16 u) {
    return __uint_as_float(((unsigned int)u) << 16);
}

// ---- init: deg=1 (self-loop), count=0 -------------------------------------
__global__ __launch_bounds__(256) void init_k(float* __restrict__ deg,
                                              int* __restrict__ count) {
    int i = blockIdx.x * 256 + threadIdx.x;
    if (i < NN) { deg[i] = 1.0f; count[i] = 0; }
}

__global__ __launch_bounds__(256) void deg_k(const int* __restrict__ ei,
                                             const float* __restrict__ ew,
                                             float* __restrict__ deg) {
    int e = blockIdx.x * 256 + threadIdx.x;     // grid exact: 3125*256 == NE
    atomicAdd(&deg[ei[NE + e]], ew[e]);
}

// ---- fill buckets: e2[dst*BC+pos] = {src, coef} ---------------------------
__global__ __launch_bounds__(256) void fill_k(const int* __restrict__ ei,
                                              const float* __restrict__ ew,
                                              const float* __restrict__ deg,
                                              int* __restrict__ count,
                                              int2* __restrict__ e2) {
    int e = blockIdx.x * 256 + threadIdx.x;     // grid exact
    int src = ei[e];
    int dst = ei[NE + e];
    float coef = rsqrtf(deg[src]) * ew[e] * rsqrtf(deg[dst]);
    int pos = atomicAdd(&count[dst], 1);
    if (pos < BC)                               // deg>BC has P~1e-33; guard anyway
        e2[(size_t)dst * BC + pos] = make_int2(src, __float_as_int(coef));
}

// ---- MFMA GEMM: out = A[rows,K] @ W[K,64] (+ bias) ------------------------
// mfma_f32_16x16x32_bf16: A[m=lane&15][k=quad*8+j]; B[k=quad*8+j][n=lane&15];
// C/D: col=lane&15, row=quad*4+reg. W fp32 -> bf16 LDS pre-swizzled (ds_read_b128).
template <int K, bool A_FP32, bool BIAS, bool OUT_F32>
__global__ __launch_bounds__(256) void gcn_gemm(const void* __restrict__ Ain,
                                                const float* __restrict__ Wg,
                                                const float* __restrict__ bias,
                                                void* __restrict__ outp,
                                                int rowtiles) {
    constexpr int KT = K / 32;
    __shared__ u16 Blds[KT * 256 * 8];
    int tid = threadIdx.x;
    for (int idx = tid; idx < KT * 256; idx += 256) {
        int kt = idx >> 8;
        int rem = idx & 255;
        int ct = rem >> 6;
        int ln = rem & 63;
        int kb = kt * 32 + (ln >> 4) * 8;
        int col = ct * 16 + (ln & 15);
#pragma unroll
        for (int j = 0; j < 8; j++)
            Blds[idx * 8 + j] = f2b(Wg[(kb + j) * 64 + col]);
    }
    __syncthreads();

    int wave = tid >> 6, lane = tid & 63;
    int rowtile = blockIdx.x * 4 + wave;
    if (rowtile >= rowtiles) return;
    int rowbase = rowtile * 16;
    int m = lane & 15, quad = lane >> 4;

    f4 acc[4];
#pragma unroll
    for (int ct = 0; ct < 4; ct++) acc[ct] = 0.0f;

    const short8* Bfrag = (const short8*)Blds;
#pragma unroll
    for (int kt = 0; kt < KT; kt++) {
        short8 af;
        if (A_FP32) {
            const float* A = (const float*)Ain;
            const f4* p = (const f4*)&A[(size_t)(rowbase + m) * K + kt * 32 + quad * 8];
            f4 v0 = p[0], v1 = p[1];
#pragma unroll
            for (int j = 0; j < 4; j++) {
                af[j]     = (short)f2b(v0[j]);
                af[4 + j] = (short)f2b(v1[j]);
            }
        } else {
            const u16* A = (const u16*)Ain;
            af = *(const short8*)&A[(size_t)(rowbase + m) * K + kt * 32 + quad * 8];
        }
#pragma unroll
        for (int ct = 0; ct < 4; ct++) {
            short8 bf = Bfrag[(kt * 4 + ct) * 64 + lane];
            acc[ct] = __builtin_amdgcn_mfma_f32_16x16x32_bf16(af, bf, acc[ct], 0, 0, 0);
        }
    }

#pragma unroll
    for (int ct = 0; ct < 4; ct++) {
        int col = ct * 16 + m;
        float bc = BIAS ? bias[col] : 0.0f;
#pragma unroll
        for (int r = 0; r < 4; r++) {
            int row = rowbase + quad * 4 + r;
            float v = acc[ct][r] + bc;
            if (OUT_F32) ((float*)outp)[(size_t)row * 64 + col] = v;
            else         ((u16*)outp)[(size_t)row * 64 + col] = f2b(v);
        }
    }
}

// ---- gather core: acc += sum coef*h[src] over bucket, unroll x4 -----------
__device__ __forceinline__ void gather_edges(const int2* __restrict__ eb, int cnt,
                                             const u16* __restrict__ hb, int ch,
                                             f4& acc, float& cs) {
    int i = 0;
    for (; i + 3 < cnt; i += 4) {
        int2 q0 = eb[i], q1 = eb[i + 1], q2 = eb[i + 2], q3 = eb[i + 3];
        u16x4 h0 = *(const u16x4*)&hb[(size_t)q0.x * 64 + ch * 4];
        u16x4 h1 = *(const u16x4*)&hb[(size_t)q1.x * 64 + ch * 4];
        u16x4 h2 = *(const u16x4*)&hb[(size_t)q2.x * 64 + ch * 4];
        u16x4 h3 = *(const u16x4*)&hb[(size_t)q3.x * 64 + ch * 4];
        float c0 = __int_as_float(q0.y), c1 = __int_as_float(q1.y);
        float c2 = __int_as_float(q2.y), c3 = __int_as_float(q3.y);
#pragma unroll
        for (int j = 0; j < 4; j++) {
            acc[j] = fmaf(c0, b2f(h0[j]), acc[j]);
            acc[j] = fmaf(c1, b2f(h1[j]), acc[j]);
            acc[j] = fmaf(c2, b2f(h2[j]), acc[j]);
            acc[j] = fmaf(c3, b2f(h3[j]), acc[j]);
        }
        cs += (c0 + c1) + (c2 + c3);
    }
    for (; i < cnt; i++) {
        int2 q0 = eb[i];
        float c0 = __int_as_float(q0.y);
        u16x4 h0 = *(const u16x4*)&hb[(size_t)q0.x * 64 + ch * 4];
#pragma unroll
        for (int j = 0; j < 4; j++) acc[j] = fmaf(c0, b2f(h0[j]), acc[j]);
        cs += c0;
    }
}

// ---- gather1: agg1 = relu(A*h + rowsum(A)*bmW1 + b1), bf16 out ------------
// 16 threads/row, 16 rows/block. bmW1 = bm@W1 computed per block into LDS.
__global__ __launch_bounds__(256) void gather1_k(const int2* __restrict__ e2,
                                                 const int* __restrict__ count,
                                                 const float* __restrict__ deg,
                                                 const u16* __restrict__ hb,
                                                 const float* __restrict__ bm,
                                                 const float* __restrict__ W1,
                                                 const float* __restrict__ b1,
                                                 u16* __restrict__ outb) {
    __shared__ float bmw1s[64];
    int tid = threadIdx.x;
    if (tid < 64) {
        float a = 0.0f;
#pragma unroll 8
        for (int k = 0; k < 64; k++) a = fmaf(bm[k], W1[k * 64 + tid], a);
        bmw1s[tid] = a;
    }
    __syncthreads();

    int dst = blockIdx.x * 16 + (tid >> 4);    // grid exact: 6250*16 == NN
    int ch = tid & 15;
    int cnt = min(count[dst], BC);
    float d = rsqrtf(deg[dst]);
    float d2 = d * d;

    f4 acc = 0.0f;
    float cs = 0.0f;
    gather_edges(&e2[(size_t)dst * BC], cnt, hb, ch, acc, cs);

    u16x4 hs = *(const u16x4*)&hb[(size_t)dst * 64 + ch * 4];
#pragma unroll
    for (int j = 0; j < 4; j++) acc[j] = fmaf(d2, b2f(hs[j]), acc[j]);

    float s = d2 + cs;                         // rowsum of normalized adjacency
    u16x4 o;
#pragma unroll
    for (int j = 0; j < 4; j++) {
        float v = fmaf(s, bmw1s[ch * 4 + j], acc[j]) + b1[ch * 4 + j];
        o[j] = f2b(fmaxf(v, 0.0f));            // fused relu
    }
    ((u16x4*)outb)[(size_t)dst * 16 + ch] = o;
}

// ---- fused gather2 + final GEMM: out = (A*agg1)@W2 + b2, fp32 -------------
// 16 rows/block gathered into padded LDS A-tile; wave 0 does 16x64 @ 64x64 MFMA.
__global__ __launch_bounds__(256) void g2gemm_k(const int2* __restrict__ e2,
                                                const int* __restrict__ count,
                                                const float* __restrict__ deg,
                                                const u16* __restrict__ aggb,
                                                const float* __restrict__ W2,
                                                const float* __restrict__ b2,
                                                float* __restrict__ out) {
    __shared__ u16 Wlds[2 * 256 * 8];          // swizzled B frags (8 KB)
    __shared__ u16 Atile[16][72];              // 16 rows x 64 bf16, +8 pad (144 B rows)
    int tid = threadIdx.x;
    for (int idx = tid; idx < 2 * 256; idx += 256) {
        int kt = idx >> 8;
        int rem = idx & 255;
        int ct = rem >> 6;
        int ln = rem & 63;
        int kb = kt * 32 + (ln >> 4) * 8;
        int col = ct * 16 + (ln & 15);
#pragma unroll
        for (int j = 0; j < 8; j++)
            Wlds[idx * 8 + j] = f2b(W2[(kb + j) * 64 + col]);
    }

    int r = tid >> 4, ch = tid & 15;
    int dst = blockIdx.x * 16 + r;             // grid exact: 6250*16 == NN
    int cnt = min(count[dst], BC);
    float d = rsqrtf(deg[dst]);
    float d2 = d * d;

    f4 acc = 0.0f;
    float cs = 0.0f;
    gather_edges(&e2[(size_t)dst * BC], cnt, aggb, ch, acc, cs);

    u16x4 hs = *(const u16x4*)&aggb[(size_t)dst * 64 + ch * 4];
    u16x4 o;
#pragma unroll
    for (int j = 0; j < 4; j++) o[j] = f2b(fmaf(d2, b2f(hs[j]), acc[j]));
    *(u16x4*)&Atile[r][ch * 4] = o;
    __syncthreads();

    if (tid >= 64) return;                     // wave 0 computes the MFMA
    int m = tid & 15, quad = tid >> 4;
    f4 cacc[4];
#pragma unroll
    for (int ct = 0; ct < 4; ct++) cacc[ct] = 0.0f;
    const short8* Bfrag = (const short8*)Wlds;
#pragma unroll
    for (int kt = 0; kt < 2; kt++) {
        short8 af = *(const short8*)&Atile[m][kt * 32 + quad * 8];
#pragma unroll
        for (int ct = 0; ct < 4; ct++)
            cacc[ct] = __builtin_amdgcn_mfma_f32_16x16x32_bf16(af, Bfrag[(kt * 4 + ct) * 64 + tid], cacc[ct], 0, 0, 0);
    }
    int rowbase = blockIdx.x * 16;
#pragma unroll
    for (int ct = 0; ct < 4; ct++) {
        int col = ct * 16 + m;
        float bc = b2[col];
#pragma unroll
        for (int rr = 0; rr < 4; rr++)
            out[(size_t)(rowbase + quad * 4 + rr) * 64 + col] = cacc[ct][rr] + bc;
    }
}

extern "C" void kernel_launch(void* const* d_in, const int* in_sizes, int n_in,
                              void* d_out, int out_size, void* d_ws, size_t ws_size,
                              hipStream_t stream) {
    const float* x  = (const float*)d_in[0];
    const int*   ei = (const int*)d_in[1];
    const float* ew = (const float*)d_in[2];
    const float* Wm = (const float*)d_in[3];
    const float* bm = (const float*)d_in[4];
    const float* W1 = (const float*)d_in[5];
    const float* b1 = (const float*)d_in[6];
    const float* W2 = (const float*)d_in[7];
    const float* b2 = (const float*)d_in[8];
    float* out = (float*)d_out;

    // ws layout (offsets in bytes)
    char*  w     = (char*)d_ws;
    float* deg   = (float*)(w);                 // NN f32 (400 KB)
    int*   count = (int*)(w + (512 << 10));     // NN i32
    float* Wf    = (float*)(w + (1 << 20));     // 384*64 f32 (98 KB)
    int2*  e2    = (int2*)(w + (4 << 20));      // NN*BC int2 (51.2 MB)
    u16*   hb    = (u16*)(w + (64u << 20));     // NN*64 bf16 (12.8 MB)
    u16*   aggb  = (u16*)(w + (80u << 20));     // NN*64 bf16

    init_k<<<391, 256, 0, stream>>>(deg, count);
    deg_k<<<3125, 256, 0, stream>>>(ei, ew, deg);
    fill_k<<<3125, 256, 0, stream>>>(ei, ew, deg, count, e2);

    // Wf = Wm @ W1 (384x64 fp32)
    gcn_gemm<64, true, false, true><<<6, 256, 0, stream>>>(Wm, W1, nullptr, Wf, 24);
    // h1' = x @ Wf (bf16)
    gcn_gemm<384, true, false, false><<<1563, 256, 0, stream>>>(x, Wf, nullptr, hb, 6250);
    // agg1 = relu(A*h1' + rowsum(A)*(bm@W1) + b1)  (bf16)
    gather1_k<<<6250, 256, 0, stream>>>(e2, count, deg, hb, bm, W1, b1, aggb);
    // out = (A*agg1)@W2 + b2  (fp32)
    g2gemm_k<<<6250, 256, 0, stream>>>(e2, count, deg, aggb, W2, b2, out);
}

// Round 6
// 424.743 us; speedup vs baseline: 1.5975x; 1.0014x over previous
//
#include <hip/hip_runtime.h>

// DynamicGCN: x[100000,384] fp32 -> Linear(384,64) -> GCNConv(64,64) -> ReLU -> GCNConv(64,64)
// Round 6: gather MLP restructure (masked 8-wide full-prefetch batches) + fat
// init||Wf kernel (6 dispatches).
//   - Bucketed CSR (64 slots/dst, atomic fill, no scan)
//   - Layer1 fused: Wf = Wm@W1; ONE K=384 GEMM; gather1 adds rowsum(A)*(bm@W1)+b1+relu
//   - Layer2 commuted: gather2 fused with final MFMA GEMM -> d_out
// Intermediates bf16, accumulation fp32 throughout.

#define NN 100000
#define NE 800000
#define BC 64          // bucket capacity per dst row

typedef unsigned short u16;
typedef __attribute__((ext_vector_type(8))) short short8;   // 8 bf16 (MFMA A/B frag)
typedef __attribute__((ext_vector_type(4))) float f4;       // MFMA C/D frag
typedef __attribute__((ext_vector_type(4))) unsigned short u16x4;

__device__ __forceinline__ u16 f2b(float f) {   // RNE fp32 -> bf16
    unsigned int x = __float_as_uint(f);
    x += 0x7fffu + ((x >> 16) & 1u);
    return (u16)(x >> 16);
}
__device__ __forceinline__ float b2f(u16 u) {
    return __uint_as_float(((unsigned int)u) << 16);
}

// ---- fat kernel: blocks 0..390 init deg/count; blocks 391..396 Wf = Wm@W1 --
__global__ __launch_bounds__(256) void init_wf_k(float* __restrict__ deg,
                                                 int* __restrict__ count,
                                                 const float* __restrict__ Wm,
                                                 const float* __restrict__ W1,
                                                 float* __restrict__ Wf) {
    __shared__ u16 Blds[2 * 256 * 8];
    int tid = threadIdx.x;
    if (blockIdx.x < 391) {
        int i = blockIdx.x * 256 + tid;
        if (i < NN) { deg[i] = 1.0f; count[i] = 0; }
        return;
    }
    // ---- Wf = Wm[384,64] @ W1[64,64], fp32 out (24 rowtiles over 6 blocks) ----
    for (int idx = tid; idx < 2 * 256; idx += 256) {
        int kt = idx >> 8, rem = idx & 255;
        int ct = rem >> 6, ln = rem & 63;
        int kb = kt * 32 + (ln >> 4) * 8;
        int col = ct * 16 + (ln & 15);
#pragma unroll
        for (int j = 0; j < 8; j++)
            Blds[idx * 8 + j] = f2b(W1[(kb + j) * 64 + col]);
    }
    __syncthreads();
    int wave = tid >> 6, lane = tid & 63;
    int rowtile = (blockIdx.x - 391) * 4 + wave;   // 0..23
    int rowbase = rowtile * 16;
    int m = lane & 15, quad = lane >> 4;
    f4 acc[4];
#pragma unroll
    for (int ct = 0; ct < 4; ct++) acc[ct] = 0.0f;
    const short8* Bfrag = (const short8*)Blds;
#pragma unroll
    for (int kt = 0; kt < 2; kt++) {
        const f4* p = (const f4*)&Wm[(size_t)(rowbase + m) * 64 + kt * 32 + quad * 8];
        f4 v0 = p[0], v1 = p[1];
        short8 af;
#pragma unroll
        for (int j = 0; j < 4; j++) {
            af[j]     = (short)f2b(v0[j]);
            af[4 + j] = (short)f2b(v1[j]);
        }
#pragma unroll
        for (int ct = 0; ct < 4; ct++)
            acc[ct] = __builtin_amdgcn_mfma_f32_16x16x32_bf16(af, Bfrag[(kt * 4 + ct) * 64 + lane], acc[ct], 0, 0, 0);
    }
#pragma unroll
    for (int ct = 0; ct < 4; ct++) {
        int col = ct * 16 + m;
#pragma unroll
        for (int r = 0; r < 4; r++)
            Wf[(size_t)(rowbase + quad * 4 + r) * 64 + col] = acc[ct][r];
    }
}

__global__ __launch_bounds__(256) void deg_k(const int* __restrict__ ei,
                                             const float* __restrict__ ew,
                                             float* __restrict__ deg) {
    int e = blockIdx.x * 256 + threadIdx.x;     // grid exact: 3125*256 == NE
    atomicAdd(&deg[ei[NE + e]], ew[e]);
}

// ---- fill buckets: e2[dst*BC+pos] = {src, coef} ---------------------------
__global__ __launch_bounds__(256) void fill_k(const int* __restrict__ ei,
                                              const float* __restrict__ ew,
                                              const float* __restrict__ deg,
                                              int* __restrict__ count,
                                              int2* __restrict__ e2) {
    int e = blockIdx.x * 256 + threadIdx.x;     // grid exact
    int src = ei[e];
    int dst = ei[NE + e];
    float coef = rsqrtf(deg[src]) * ew[e] * rsqrtf(deg[dst]);
    int pos = atomicAdd(&count[dst], 1);
    if (pos < BC)                               // P(deg>BC) ~ 1e-33; guard anyway
        e2[(size_t)dst * BC + pos] = make_int2(src, __float_as_int(coef));
}

// ---- MFMA GEMM: out = A[rows,K] @ W[K,64] ---------------------------------
// mfma_f32_16x16x32_bf16: A[m=lane&15][k=quad*8+j]; B[k=quad*8+j][n=lane&15];
// C/D: col=lane&15, row=quad*4+reg. W fp32 -> bf16 LDS pre-swizzled (ds_read_b128).
template <int K>
__global__ __launch_bounds__(256) void gcn_gemm(const float* __restrict__ Ain,
                                                const float* __restrict__ Wg,
                                                u16* __restrict__ outb,
                                                int rowtiles) {
    constexpr int KT = K / 32;
    __shared__ u16 Blds[KT * 256 * 8];
    int tid = threadIdx.x;
    for (int idx = tid; idx < KT * 256; idx += 256) {
        int kt = idx >> 8, rem = idx & 255;
        int ct = rem >> 6, ln = rem & 63;
        int kb = kt * 32 + (ln >> 4) * 8;
        int col = ct * 16 + (ln & 15);
#pragma unroll
        for (int j = 0; j < 8; j++)
            Blds[idx * 8 + j] = f2b(Wg[(kb + j) * 64 + col]);
    }
    __syncthreads();

    int wave = tid >> 6, lane = tid & 63;
    int rowtile = blockIdx.x * 4 + wave;
    if (rowtile >= rowtiles) return;
    int rowbase = rowtile * 16;
    int m = lane & 15, quad = lane >> 4;

    f4 acc[4];
#pragma unroll
    for (int ct = 0; ct < 4; ct++) acc[ct] = 0.0f;

    const short8* Bfrag = (const short8*)Blds;
#pragma unroll
    for (int kt = 0; kt < KT; kt++) {
        const f4* p = (const f4*)&Ain[(size_t)(rowbase + m) * K + kt * 32 + quad * 8];
        f4 v0 = p[0], v1 = p[1];
        short8 af;
#pragma unroll
        for (int j = 0; j < 4; j++) {
            af[j]     = (short)f2b(v0[j]);
            af[4 + j] = (short)f2b(v1[j]);
        }
#pragma unroll
        for (int ct = 0; ct < 4; ct++)
            acc[ct] = __builtin_amdgcn_mfma_f32_16x16x32_bf16(af, Bfrag[(kt * 4 + ct) * 64 + lane], acc[ct], 0, 0, 0);
    }

#pragma unroll
    for (int ct = 0; ct < 4; ct++) {
        int col = ct * 16 + m;
#pragma unroll
        for (int r = 0; r < 4; r++)
            outb[(size_t)(rowbase + quad * 4 + r) * 64 + col] = f2b(acc[ct][r]);
    }
}

// ---- gather core: masked 8-wide batches, full prefetch (MLP=8) ------------
__device__ __forceinline__ void gather_edges(const int2* __restrict__ eb, int cnt,
                                             const u16* __restrict__ hb, int ch,
                                             f4& acc, float& cs) {
    for (int i = 0; i < cnt; i += 8) {
        int2 q[8];
#pragma unroll
        for (int t = 0; t < 8; t++) {
            int idx = (i + t < cnt) ? i + t : i;   // masked: reload rec 0 (line hot)
            q[t] = eb[idx];
        }
        u16x4 h[8];
#pragma unroll
        for (int t = 0; t < 8; t++)
            h[t] = *(const u16x4*)&hb[(size_t)q[t].x * 64 + ch * 4];
#pragma unroll
        for (int t = 0; t < 8; t++) {
            float c = (i + t < cnt) ? __int_as_float(q[t].y) : 0.0f;
            cs += c;
#pragma unroll
            for (int j = 0; j < 4; j++) acc[j] = fmaf(c, b2f(h[t][j]), acc[j]);
        }
    }
}

// ---- gather1: agg1 = relu(A*h + rowsum(A)*bmW1 + b1), bf16 out ------------
// 16 threads/row, 16 rows/block. bmW1 = bm@W1 computed per block into LDS.
__global__ __launch_bounds__(256) void gather1_k(const int2* __restrict__ e2,
                                                 const int* __restrict__ count,
                                                 const float* __restrict__ deg,
                                                 const u16* __restrict__ hb,
                                                 const float* __restrict__ bm,
                                                 const float* __restrict__ W1,
                                                 const float* __restrict__ b1,
                                                 u16* __restrict__ outb) {
    __shared__ float bmw1s[64];
    int tid = threadIdx.x;
    if (tid < 64) {
        float a = 0.0f;
#pragma unroll 8
        for (int k = 0; k < 64; k++) a = fmaf(bm[k], W1[k * 64 + tid], a);
        bmw1s[tid] = a;
    }
    __syncthreads();

    int dst = blockIdx.x * 16 + (tid >> 4);    // grid exact: 6250*16 == NN
    int ch = tid & 15;
    int cnt = min(count[dst], BC);
    float d2 = 1.0f / deg[dst];                // dinv^2 exactly

    f4 acc = 0.0f;
    float cs = 0.0f;
    gather_edges(&e2[(size_t)dst * BC], cnt, hb, ch, acc, cs);

    u16x4 hs = *(const u16x4*)&hb[(size_t)dst * 64 + ch * 4];
#pragma unroll
    for (int j = 0; j < 4; j++) acc[j] = fmaf(d2, b2f(hs[j]), acc[j]);

    float s = d2 + cs;                         // rowsum of normalized adjacency
    u16x4 o;
#pragma unroll
    for (int j = 0; j < 4; j++) {
        float v = fmaf(s, bmw1s[ch * 4 + j], acc[j]) + b1[ch * 4 + j];
        o[j] = f2b(fmaxf(v, 0.0f));            // fused relu
    }
    ((u16x4*)outb)[(size_t)dst * 16 + ch] = o;
}

// ---- fused gather2 + final GEMM: out = (A*agg1)@W2 + b2, fp32 -------------
__global__ __launch_bounds__(256) void g2gemm_k(const int2* __restrict__ e2,
                                                const int* __restrict__ count,
                                                const float* __restrict__ deg,
                                                const u16* __restrict__ aggb,
                                                const float* __restrict__ W2,
                                                const float* __restrict__ b2,
                                                float* __restrict__ out) {
    __shared__ u16 Wlds[2 * 256 * 8];          // swizzled B frags (8 KB)
    __shared__ u16 Atile[16][72];              // 16x64 bf16 rows, +8 pad
    int tid = threadIdx.x;
    for (int idx = tid; idx < 2 * 256; idx += 256) {
        int kt = idx >> 8, rem = idx & 255;
        int ct = rem >> 6, ln = rem & 63;
        int kb = kt * 32 + (ln >> 4) * 8;
        int col = ct * 16 + (ln & 15);
#pragma unroll
        for (int j = 0; j < 8; j++)
            Wlds[idx * 8 + j] = f2b(W2[(kb + j) * 64 + col]);
    }

    int r = tid >> 4, ch = tid & 15;
    int dst = blockIdx.x * 16 + r;             // grid exact: 6250*16 == NN
    int cnt = min(count[dst], BC);
    float d2 = 1.0f / deg[dst];

    f4 acc = 0.0f;
    float cs = 0.0f;
    gather_edges(&e2[(size_t)dst * BC], cnt, aggb, ch, acc, cs);

    u16x4 hs = *(const u16x4*)&aggb[(size_t)dst * 64 + ch * 4];
    u16x4 o;
#pragma unroll
    for (int j = 0; j < 4; j++) o[j] = f2b(fmaf(d2, b2f(hs[j]), acc[j]));
    *(u16x4*)&Atile[r][ch * 4] = o;
    __syncthreads();

    if (tid >= 64) return;                     // wave 0 computes the MFMA
    int m = tid & 15, quad = tid >> 4;
    f4 cacc[4];
#pragma unroll
    for (int ct = 0; ct < 4; ct++) cacc[ct] = 0.0f;
    const short8* Bfrag = (const short8*)Wlds;
#pragma unroll
    for (int kt = 0; kt < 2; kt++) {
        short8 af = *(const short8*)&Atile[m][kt * 32 + quad * 8];
#pragma unroll
        for (int ct = 0; ct < 4; ct++)
            cacc[ct] = __builtin_amdgcn_mfma_f32_16x16x32_bf16(af, Bfrag[(kt * 4 + ct) * 64 + tid], cacc[ct], 0, 0, 0);
    }
    int rowbase = blockIdx.x * 16;
#pragma unroll
    for (int ct = 0; ct < 4; ct++) {
        int col = ct * 16 + m;
        float bc = b2[col];
#pragma unroll
        for (int rr = 0; rr < 4; rr++)
            out[(size_t)(rowbase + quad * 4 + rr) * 64 + col] = cacc[ct][rr] + bc;
    }
}

extern "C" void kernel_launch(void* const* d_in, const int* in_sizes, int n_in,
                              void* d_out, int out_size, void* d_ws, size_t ws_size,
                              hipStream_t stream) {
    const float* x  = (const float*)d_in[0];
    const int*   ei = (const int*)d_in[1];
    const float* ew = (const float*)d_in[2];
    const float* Wm = (const float*)d_in[3];
    const float* bm = (const float*)d_in[4];
    const float* W1 = (const float*)d_in[5];
    const float* b1 = (const float*)d_in[6];
    const float* W2 = (const float*)d_in[7];
    const float* b2 = (const float*)d_in[8];
    float* out = (float*)d_out;

    // ws layout (offsets in bytes)
    char*  w     = (char*)d_ws;
    float* deg   = (float*)(w);                 // NN f32 (400 KB)
    int*   count = (int*)(w + (512 << 10));     // NN i32
    float* Wf    = (float*)(w + (1 << 20));     // 384*64 f32 (98 KB)
    int2*  e2    = (int2*)(w + (4 << 20));      // NN*BC int2 (51.2 MB)
    u16*   hb    = (u16*)(w + (64u << 20));     // NN*64 bf16 (12.8 MB)
    u16*   aggb  = (u16*)(w + (80u << 20));     // NN*64 bf16

    init_wf_k<<<397, 256, 0, stream>>>(deg, count, Wm, W1, Wf);
    deg_k<<<3125, 256, 0, stream>>>(ei, ew, deg);
    fill_k<<<3125, 256, 0, stream>>>(ei, ew, deg, count, e2);

    // h1' = x @ Wf (bf16)
    gcn_gemm<384><<<1563, 256, 0, stream>>>(x, Wf, hb, 6250);
    // agg1 = relu(A*h1' + rowsum(A)*(bm@W1) + b1)  (bf16)
    gather1_k<<<6250, 256, 0, stream>>>(e2, count, deg, hb, bm, W1, b1, aggb);
    // out = (A*agg1)@W2 + b2  (fp32)
    g2gemm_k<<<6250, 256, 0, stream>>>(e2, count, deg, aggb, W2, b2, out);
}